// Round 11
// baseline (51.125 us; speedup 1.0000x reference)
//
#include <hip/hip_runtime.h>
#include <hip/hip_bf16.h>

// VQ-VAE vector quantizer, MI355X — E-resident, 1024-thr (4 waves/SIMD).
// [k_prep]  64 blocks: emb -> swizzled fp8 E (x512) + cn=||e||^2 fp32; loss=0
// [k_fused] 256 blocks x 1024thr (1/CU, 16 waves = 4/SIMD): 128 hw rows of one b.
//   - stage fp8 E (128KB) + cn (4KB) via global_load_lds w16
//   - lat loads fully coalesced (thread = row x 16-d slice), cvt fp8 -> ldsA b128
//   - phase B: wave (g=w>>2, q=w&3) = rows [32g,+32) x codes [256q,+256).
//     av[2][4] cached; per c-tile 4 bv ds_read_b64 -> 8 MFMA; fold fp32.
//   - 16-lane butterfly (8 pairs/wave) -> ms/mi[4][128] -> 4-way merge
//   - gather q=emb[k*] fp32 -> [B,D,H,W], one loss atomicAdd per block

typedef __attribute__((ext_vector_type(4))) float f32x4;

// workspace layout (bytes)
#define WS_E 0u          // fp8 swz [1024][128] = 131072
#define WS_C 131072u     // f32 cn[1024]        = 4096

#define LOSS_SCALE (1.25f / 4194304.0f)
#define NEG2_INV_LAMBDA (-2.0f / 512.0f)

static __device__ inline unsigned cvt4_fp8(float a, float b, float c, float d) {
    int v = __builtin_amdgcn_cvt_pk_fp8_f32(a, b, 0, false);
    v = __builtin_amdgcn_cvt_pk_fp8_f32(c, d, v, true);
    return (unsigned)v;
}

static __device__ inline void gload_lds16(const void* g, void* l) {
    __builtin_amdgcn_global_load_lds(
        (const __attribute__((address_space(1))) unsigned int*)g,
        (__attribute__((address_space(3))) unsigned int*)l, 16, 0, 0);
}

// ---------------- codebook prep ----------------
__global__ __launch_bounds__(256) void k_prep(const float* __restrict__ emb,
                                              char* __restrict__ Eb,
                                              float* __restrict__ cn,
                                              float* __restrict__ loss) {
    const int t = threadIdx.x;
    const int row = (blockIdx.x << 4) + (t >> 4), c = t & 15;
    const float4* ep = (const float4*)(emb + ((size_t)row << 7) + (c << 3));
    float4 e0 = ep[0], e1 = ep[1];
    float s = e0.x*e0.x + e0.y*e0.y + e0.z*e0.z + e0.w*e0.w
            + e1.x*e1.x + e1.y*e1.y + e1.z*e1.z + e1.w*e1.w;
#pragma unroll
    for (int m = 1; m < 16; m <<= 1) s += __shfl_xor(s, m);
    if (c == 0) cn[row] = s;
    uint2 v;
    v.x = cvt4_fp8(512.f*e0.x, 512.f*e0.y, 512.f*e0.z, 512.f*e0.w);
    v.y = cvt4_fp8(512.f*e1.x, 512.f*e1.y, 512.f*e1.z, 512.f*e1.w);
    *(uint2*)(Eb + row * 128 + ((c * 8) ^ ((row & 7) << 4))) = v;
    if (blockIdx.x == 0 && t == 0) loss[0] = 0.f;
}

// ---------------- fused: E-resident scoring + gather, 1024 thr ----------------
// LDS: E @0 (128K) | A @131072 (16K) | C @147456 (4K) | ms @151552 (2K) |
//      mi @153600 (2K) | win @155648 (512) | bsum @156160 (512) | rs @156672 (64)
//      = 156736 B (<=163840), 1 block/CU.
__global__ __launch_bounds__(1024, 4) void k_fused(const float* __restrict__ lat,
                                                   const float* __restrict__ emb,
                                                   const char* __restrict__ Eb,
                                                   const float* __restrict__ cn,
                                                   float* __restrict__ outq,
                                                   float* __restrict__ loss) {
    __shared__ __align__(16) char lds[156736];
    char*  ldsE = lds;                           // fp8 swz [1024][128]
    char*  ldsA = lds + 131072;                  // fp8 swz [128][128]
    float* ldsC = (float*)(lds + 147456);        // [1024]
    float* ms   = (float*)(lds + 151552);        // [4][128]
    int*   mi   = (int*)  (lds + 153600);        // [4][128]
    int*   win  = (int*)  (lds + 155648);        // [128]
    float* bsum = (float*)(lds + 156160);        // [128]
    float* rs   = (float*)(lds + 156672);        // [16]

    const int t = threadIdx.x, bm = blockIdx.x;  // 256 blocks
    const int lane = t & 63, w = t >> 6;         // 16 waves
    const int l15 = lane & 15, lg = lane >> 4;
    const int b = bm >> 3, hw0 = (bm & 7) << 7;  // 128 rows

    // ---- stage E (128 KB) + cn (4 KB); latency hides under lat load/cvt ----
#pragma unroll
    for (int i = 0; i < 8; ++i) {
        int base = i * 16384 + (w << 10);        // wave-uniform byte base
        gload_lds16(Eb + base + lane * 16, ldsE + base);
    }
    if (w < 4) gload_lds16((const char*)cn + (w << 10) + lane * 16,
                           (char*)ldsC + (w << 10));

    // ---- lat: thread = (rowl, 16-d slice); fully coalesced 256B/instr ----
    const int rowl = t & 127, dgrp = t >> 7;     // 8 dgrps x 16 d
    {
        const float* lp = lat + ((size_t)b << 17) + ((size_t)(dgrp << 4) << 10) + hw0 + rowl;
        float lv[16];
#pragma unroll
        for (int j = 0; j < 16; ++j) lv[j] = lp[(size_t)j << 10];
        float rn = 0.f;
#pragma unroll
        for (int j = 0; j < 16; ++j) rn = fmaf(lv[j], lv[j], rn);
        uint4 wv;
        wv.x = cvt4_fp8(lv[0],  lv[1],  lv[2],  lv[3]);
        wv.y = cvt4_fp8(lv[4],  lv[5],  lv[6],  lv[7]);
        wv.z = cvt4_fp8(lv[8],  lv[9],  lv[10], lv[11]);
        wv.w = cvt4_fp8(lv[12], lv[13], lv[14], lv[15]);
        *(uint4*)(ldsA + rowl * 128 + ((dgrp << 4) ^ ((rowl & 7) << 4))) = wv;
#pragma unroll
        for (int m = 1; m < 64; m <<= 1) rn += __shfl_xor(rn, m);
        if (lane == 0) rs[w] = rn;
    }
    __syncthreads();     // E + cn staged (vmcnt), A-tile written (lgkm)

    // ---- phase B: wave (g,q) = rows [32g,+32) x codes [256q,+256) ----
    const int g = w >> 2, q = w & 3;
    const int swz = 0;   (void)swz;
    long av[2][4];
#pragma unroll
    for (int m = 0; m < 2; ++m)
#pragma unroll
        for (int ks = 0; ks < 4; ++ks) {
            int r = (g << 5) + m * 16 + l15;
            av[m][ks] = *(const long*)(ldsA + r * 128 +
                                       ((ks * 32 + lg * 8) ^ ((r & 7) << 4)));
        }

    float run_s[2][4]; int run_i[2][4];
#pragma unroll
    for (int m = 0; m < 2; ++m)
#pragma unroll
        for (int r = 0; r < 4; ++r) { run_s[m][r] = 3.0e38f; run_i[m][r] = 0; }

#pragma unroll
    for (int c2 = 0; c2 < 16; ++c2) {
        const int kgb = (q << 8) + (c2 << 4);
        const int rr = kgb + l15;
        long bv[4];
#pragma unroll
        for (int ks = 0; ks < 4; ++ks)
            bv[ks] = *(const long*)(ldsE + rr * 128 +
                                    ((ks * 32 + lg * 8) ^ ((rr & 7) << 4)));
        const float cv = ldsC[rr];

        f32x4 acc[2];
#pragma unroll
        for (int m = 0; m < 2; ++m) acc[m] = (f32x4){0.f, 0.f, 0.f, 0.f};
#pragma unroll
        for (int ks = 0; ks < 4; ++ks)
#pragma unroll
            for (int m = 0; m < 2; ++m)
                acc[m] = __builtin_amdgcn_mfma_f32_16x16x32_fp8_fp8(av[m][ks], bv[ks], acc[m], 0, 0, 0);

#pragma unroll
        for (int m = 0; m < 2; ++m)
#pragma unroll
            for (int r = 0; r < 4; ++r) {
                float s = fmaf(NEG2_INV_LAMBDA, acc[m][r], cv);
                if (s < run_s[m][r]) { run_s[m][r] = s; run_i[m][r] = rr; }
            }
    }

    // ---- butterfly over 16 code-lanes; write [q][row] partials ----
#pragma unroll
    for (int m = 0; m < 2; ++m)
#pragma unroll
        for (int r = 0; r < 4; ++r) {
            float s = run_s[m][r]; int bi = run_i[m][r];
#pragma unroll
            for (int mask = 1; mask < 16; mask <<= 1) {
                float os = __shfl_xor(s, mask);
                int   oi = __shfl_xor(bi, mask);
                if (os < s || (os == s && oi < bi)) { s = os; bi = oi; }
            }
            if (l15 == 0) {
                int row = (g << 5) + m * 16 + (lg << 2) + r;   // C row = lg*4+reg
                ms[(q << 7) + row] = s;
                mi[(q << 7) + row] = bi;
            }
        }
    __syncthreads();

    // ---- 4-way merge per row (q ascending -> lowest-index tie-break) ----
    if (t < 128) {
        float bs = ms[t]; int bi = mi[t];
#pragma unroll
        for (int q2 = 1; q2 < 4; ++q2) {
            float s2 = ms[(q2 << 7) + t]; int i2 = mi[(q2 << 7) + t];
            if (s2 < bs || (s2 == bs && i2 < bi)) { bs = s2; bi = i2; }
        }
        win[t] = bi;
        bsum[t] = bs;
    }
    __syncthreads();

    if (w == 0) {        // loss partial: sum(min_s) + sum(x^2)
        float v = bsum[lane] + bsum[64 + lane];
        if (lane < 16) v += rs[lane];
#pragma unroll
        for (int m = 1; m < 64; m <<= 1) v += __shfl_xor(v, m);
        if (lane == 0) atomicAdd(loss, v * LOSS_SCALE);
    }

    // ---- gather q = emb[k*] fp32, store [B,D,H,W] coalesced ----
    {
        const int bi = win[rowl];
        const float4* eg = (const float4*)(emb + ((size_t)bi << 7) + (dgrp << 4));
        float* ob = outq + ((size_t)b << 17) + ((size_t)(dgrp << 4) << 10) + hw0 + rowl;
#pragma unroll
        for (int jj = 0; jj < 4; ++jj) {
            float4 v = eg[jj];
            ob[(size_t)(jj * 4 + 0) << 10] = v.x;
            ob[(size_t)(jj * 4 + 1) << 10] = v.y;
            ob[(size_t)(jj * 4 + 2) << 10] = v.z;
            ob[(size_t)(jj * 4 + 3) << 10] = v.w;
        }
    }
}

extern "C" void kernel_launch(void* const* d_in, const int* in_sizes, int n_in,
                              void* d_out, int out_size, void* d_ws, size_t ws_size,
                              hipStream_t stream) {
    const float* lat = (const float*)d_in[0];   // [32,128,32,32]
    const float* emb = (const float*)d_in[1];   // [1024,128]
    float* out = (float*)d_out;                 // q (4194304) + vq_loss (1)
    char* ws = (char*)d_ws;
    char*  E    = ws + WS_E;
    float* cn   = (float*)(ws + WS_C);
    float* loss = out + 4194304;

    k_prep <<<64,  256,  0, stream>>>(emb, E, cn, loss);
    k_fused<<<256, 1024, 0, stream>>>(lat, emb, E, cn, out, loss);
}

// Round 12
// 36.263 us; speedup vs baseline: 1.4099x; 1.4099x over previous
//
#include <hip/hip_runtime.h>
#include <hip/hip_bf16.h>

// VQ-VAE vector quantizer, MI355X — E-in-registers, LDS only for the A-tile.
// [k_prep]  64 blocks: emb -> PLAIN fp8 E (x512) + cn=||e||^2 fp32; loss=0
// [k_fused] 256 blocks x 1024thr (1/CU): block = 128 hw rows of one b.
//   - each wave fragment-loads its 64 codes of E into 32 VGPR (no LDS, no barrier)
//   - lat loads coalesced -> cvt fp8 -> 16KB swizzled LDS A-tile (1 barrier)
//   - phase B (barrier-free): per m-tile 4 ds_read_b64 feed 16 reg-MFMAs
//     (operands swapped: C rows = codes, C cols = imgrows); fold s=cn-(2/512)t
//   - butterfly over lg (codes axis) -> ms/mi[16][128] -> 16-way merge
//   - gather q=emb[k*] fp32 -> [B,D,H,W], one loss atomicAdd per block

typedef __attribute__((ext_vector_type(4))) float f32x4;

// workspace layout (bytes)
#define WS_E 0u          // fp8 PLAIN [1024][128] = 131072
#define WS_C 131072u     // f32 cn[1024]          = 4096

#define LOSS_SCALE (1.25f / 4194304.0f)
#define NEG2_INV_LAMBDA (-2.0f / 512.0f)

static __device__ inline unsigned cvt4_fp8(float a, float b, float c, float d) {
    int v = __builtin_amdgcn_cvt_pk_fp8_f32(a, b, 0, false);
    v = __builtin_amdgcn_cvt_pk_fp8_f32(c, d, v, true);
    return (unsigned)v;
}

// ---------------- codebook prep (PLAIN layout) ----------------
__global__ __launch_bounds__(256) void k_prep(const float* __restrict__ emb,
                                              char* __restrict__ Eb,
                                              float* __restrict__ cn,
                                              float* __restrict__ loss) {
    const int t = threadIdx.x;
    const int row = (blockIdx.x << 4) + (t >> 4), c = t & 15;
    const float4* ep = (const float4*)(emb + ((size_t)row << 7) + (c << 3));
    float4 e0 = ep[0], e1 = ep[1];
    float s = e0.x*e0.x + e0.y*e0.y + e0.z*e0.z + e0.w*e0.w
            + e1.x*e1.x + e1.y*e1.y + e1.z*e1.z + e1.w*e1.w;
#pragma unroll
    for (int m = 1; m < 16; m <<= 1) s += __shfl_xor(s, m);
    if (c == 0) cn[row] = s;
    uint2 v;
    v.x = cvt4_fp8(512.f*e0.x, 512.f*e0.y, 512.f*e0.z, 512.f*e0.w);
    v.y = cvt4_fp8(512.f*e1.x, 512.f*e1.y, 512.f*e1.z, 512.f*e1.w);
    *(uint2*)(Eb + row * 128 + c * 8) = v;
    if (blockIdx.x == 0 && t == 0) loss[0] = 0.f;
}

// ---------------- fused: E-in-regs scoring + gather ----------------
// LDS: A @0 (16K, swz) | ms @16384 (8K) | mi @24576 (8K) | win @32768 (512) |
//      bsum @33280 (512) | rs @33792 (64)  = 33856 B.
__global__ __launch_bounds__(1024, 4) void k_fused(const float* __restrict__ lat,
                                                   const float* __restrict__ emb,
                                                   const char* __restrict__ Eb,
                                                   const float* __restrict__ cn,
                                                   float* __restrict__ outq,
                                                   float* __restrict__ loss) {
    __shared__ __align__(16) char lds[33856];
    char*  ldsA = lds;                           // fp8 swz [128][128]
    float* ms   = (float*)(lds + 16384);         // [16][128]
    int*   mi   = (int*)  (lds + 24576);         // [16][128]
    int*   win  = (int*)  (lds + 32768);         // [128]
    float* bsum = (float*)(lds + 33280);         // [128]
    float* rs   = (float*)(lds + 33792);         // [16]

    const int t = threadIdx.x, bm = blockIdx.x;  // 256 blocks
    const int lane = t & 63, w = t >> 6;         // 16 waves
    const int l15 = lane & 15, lg = lane >> 4;
    const int b = bm >> 3, hw0 = (bm & 7) << 7;  // 128 rows
    const int cbase = w << 6;                    // wave's 64 codes

    // ---- E fragments straight to registers (A-operand: row l15 of each tile) ----
    long ef[4][4];                               // [ct][ks], 32 VGPR
#pragma unroll
    for (int ct = 0; ct < 4; ++ct) {
        const char* er = Eb + (size_t)(cbase + (ct << 4) + l15) * 128 + (lg << 3);
#pragma unroll
        for (int ks = 0; ks < 4; ++ks)
            ef[ct][ks] = *(const long*)(er + ks * 32);
    }
    float4 cnv[4];                               // cn[code] for C rows lg*4+r
#pragma unroll
    for (int ct = 0; ct < 4; ++ct)
        cnv[ct] = *(const float4*)(cn + cbase + (ct << 4) + (lg << 2));

    // ---- lat: coalesced loads -> fp8 -> swizzled LDS A-tile; row norms ----
    const int rowl = t & 127, dgrp = t >> 7;     // 8 dgrps x 16 d
    {
        const float* lp = lat + ((size_t)b << 17) + ((size_t)(dgrp << 4) << 10) + hw0 + rowl;
        float lv[16];
#pragma unroll
        for (int j = 0; j < 16; ++j) lv[j] = lp[(size_t)j << 10];
        float rn = 0.f;
#pragma unroll
        for (int j = 0; j < 16; ++j) rn = fmaf(lv[j], lv[j], rn);
        uint4 wv;
        wv.x = cvt4_fp8(lv[0],  lv[1],  lv[2],  lv[3]);
        wv.y = cvt4_fp8(lv[4],  lv[5],  lv[6],  lv[7]);
        wv.z = cvt4_fp8(lv[8],  lv[9],  lv[10], lv[11]);
        wv.w = cvt4_fp8(lv[12], lv[13], lv[14], lv[15]);
        *(uint4*)(ldsA + rowl * 128 + ((dgrp << 4) ^ ((rowl & 7) << 4))) = wv;
#pragma unroll
        for (int m = 1; m < 64; m <<= 1) rn += __shfl_xor(rn, m);
        if (lane == 0) rs[w] = rn;
    }
    __syncthreads();                             // A-tile ready

    // ---- phase B: barrier-free; per m-tile 4 ds_read feed 16 MFMAs ----
    float run_s[8]; int run_i[8];
#pragma unroll
    for (int m = 0; m < 8; ++m) { run_s[m] = 3.0e38f; run_i[m] = 0; }

#pragma unroll
    for (int m = 0; m < 8; ++m) {
        long bf[4];                              // B-operand: imgrow m*16+l15
#pragma unroll
        for (int ks = 0; ks < 4; ++ks)
            bf[ks] = *(const long*)(ldsA + (m * 16 + l15) * 128 +
                                    ((ks * 32 + lg * 8) ^ ((l15 & 7) << 4)));
#pragma unroll
        for (int ct = 0; ct < 4; ++ct) {
            f32x4 acc = (f32x4){0.f, 0.f, 0.f, 0.f};
#pragma unroll
            for (int ks = 0; ks < 4; ++ks)
                acc = __builtin_amdgcn_mfma_f32_16x16x32_fp8_fp8(ef[ct][ks], bf[ks], acc, 0, 0, 0);
#pragma unroll
            for (int r = 0; r < 4; ++r) {        // C row = lg*4+r (code), col = l15 (imgrow)
                float s = fmaf(NEG2_INV_LAMBDA, acc[r], cnv[ct][r]);
                if (s < run_s[m]) { run_s[m] = s; run_i[m] = cbase + (ct << 4) + (lg << 2) + r; }
            }
        }
    }

    // ---- butterfly over lg (code axis): lanes xor 16, 32 ----
#pragma unroll
    for (int m = 0; m < 8; ++m) {
        float s = run_s[m]; int bi = run_i[m];
#pragma unroll
        for (int mask = 16; mask < 64; mask <<= 1) {
            float os = __shfl_xor(s, mask);
            int   oi = __shfl_xor(bi, mask);
            if (os < s || (os == s && oi < bi)) { s = os; bi = oi; }
        }
        if (lg == 0) {
            ms[(w << 7) + m * 16 + l15] = s;
            mi[(w << 7) + m * 16 + l15] = bi;
        }
    }
    __syncthreads();

    // ---- 16-way merge per row (w ascending -> lowest-index tie-break) ----
    if (t < 128) {
        float bs = ms[t]; int bi = mi[t];
#pragma unroll
        for (int w2 = 1; w2 < 16; ++w2) {
            float s2 = ms[(w2 << 7) + t]; int i2 = mi[(w2 << 7) + t];
            if (s2 < bs || (s2 == bs && i2 < bi)) { bs = s2; bi = i2; }
        }
        win[t] = bi;
        bsum[t] = bs;
    }
    __syncthreads();

    if (w == 0) {        // loss partial: sum(min_s) + sum(x^2)
        float v = bsum[lane] + bsum[64 + lane];
        if (lane < 16) v += rs[lane];
#pragma unroll
        for (int m = 1; m < 64; m <<= 1) v += __shfl_xor(v, m);
        if (lane == 0) atomicAdd(loss, v * LOSS_SCALE);
    }

    // ---- gather q = emb[k*] fp32, store [B,D,H,W] coalesced ----
    {
        const int bi = win[rowl];
        const float4* eg = (const float4*)(emb + ((size_t)bi << 7) + (dgrp << 4));
        float* ob = outq + ((size_t)b << 17) + ((size_t)(dgrp << 4) << 10) + hw0 + rowl;
#pragma unroll
        for (int jj = 0; jj < 4; ++jj) {
            float4 v = eg[jj];
            ob[(size_t)(jj * 4 + 0) << 10] = v.x;
            ob[(size_t)(jj * 4 + 1) << 10] = v.y;
            ob[(size_t)(jj * 4 + 2) << 10] = v.z;
            ob[(size_t)(jj * 4 + 3) << 10] = v.w;
        }
    }
}

extern "C" void kernel_launch(void* const* d_in, const int* in_sizes, int n_in,
                              void* d_out, int out_size, void* d_ws, size_t ws_size,
                              hipStream_t stream) {
    const float* lat = (const float*)d_in[0];   // [32,128,32,32]
    const float* emb = (const float*)d_in[1];   // [1024,128]
    float* out = (float*)d_out;                 // q (4194304) + vq_loss (1)
    char* ws = (char*)d_ws;
    char*  E    = ws + WS_E;
    float* cn   = (float*)(ws + WS_C);
    float* loss = out + 4194304;

    k_prep <<<64,  256,  0, stream>>>(emb, E, cn, loss);
    k_fused<<<256, 1024, 0, stream>>>(lat, emb, E, cn, out, loss);
}

// Round 13
// 30.689 us; speedup vs baseline: 1.6659x; 1.1816x over previous
//
#include <hip/hip_runtime.h>
#include <hip/hip_bf16.h>

// VQ-VAE vector quantizer, MI355X — R8 (E-resident single-pass) + staggered staging.
// [k_prep]  64 blocks: emb -> swizzled fp8 E (x512) + cn=||e||^2 fp32; loss=0
// [k_fused] 256 blocks x 512thr (1/CU, 8 waves): block owns 128 hw rows of one b.
//   - stage ENTIRE fp8 E image (128KB) into LDS once, chunk order ROTATED by
//     (blockIdx & 15) so 256 CUs don't hammer the same L3 lines in lockstep
//   - A-frags direct from lat; row-norms in the same pass
//   - phase B barrier-free: wave owns 16 rows, sweeps 1024 codes from LDS
//   - in-wave butterfly, gather q=emb[k*] fp32 -> [B,D,H,W], 1 loss atomic/block

typedef __attribute__((ext_vector_type(4))) float f32x4;

// workspace layout (bytes)
#define WS_E 0u          // fp8 swz [1024][128] = 131072
#define WS_C 131072u     // f32 cn[1024]        = 4096

#define LOSS_SCALE (1.25f / 4194304.0f)
#define NEG2_INV_LAMBDA (-2.0f / 512.0f)

static __device__ inline unsigned cvt4_fp8(float a, float b, float c, float d) {
    int v = __builtin_amdgcn_cvt_pk_fp8_f32(a, b, 0, false);
    v = __builtin_amdgcn_cvt_pk_fp8_f32(c, d, v, true);
    return (unsigned)v;
}

static __device__ inline void gload_lds16(const void* g, void* l) {
    __builtin_amdgcn_global_load_lds(
        (const __attribute__((address_space(1))) unsigned int*)g,
        (__attribute__((address_space(3))) unsigned int*)l, 16, 0, 0);
}

// ---------------- codebook prep ----------------
__global__ __launch_bounds__(256) void k_prep(const float* __restrict__ emb,
                                              char* __restrict__ Eb,
                                              float* __restrict__ cn,
                                              float* __restrict__ loss) {
    const int t = threadIdx.x;
    const int row = (blockIdx.x << 4) + (t >> 4), c = t & 15;
    const float4* ep = (const float4*)(emb + ((size_t)row << 7) + (c << 3));
    float4 e0 = ep[0], e1 = ep[1];
    float s = e0.x*e0.x + e0.y*e0.y + e0.z*e0.z + e0.w*e0.w
            + e1.x*e1.x + e1.y*e1.y + e1.z*e1.z + e1.w*e1.w;
#pragma unroll
    for (int m = 1; m < 16; m <<= 1) s += __shfl_xor(s, m);
    if (c == 0) cn[row] = s;
    uint2 v;
    v.x = cvt4_fp8(512.f*e0.x, 512.f*e0.y, 512.f*e0.z, 512.f*e0.w);
    v.y = cvt4_fp8(512.f*e1.x, 512.f*e1.y, 512.f*e1.z, 512.f*e1.w);
    *(uint2*)(Eb + row * 128 + ((c * 8) ^ ((row & 7) << 4))) = v;
    if (blockIdx.x == 0 && t == 0) loss[0] = 0.f;
}

// ---------------- fused: E-resident scoring + gather ----------------
// LDS: E @0 (128K) | win @131072 (512B) | rs @131584 (32B) = 131616 B.
__global__ __launch_bounds__(512, 1) void k_fused(const float* __restrict__ lat,
                                                  const float* __restrict__ emb,
                                                  const char* __restrict__ Eb,
                                                  const float* __restrict__ cn,
                                                  float* __restrict__ outq,
                                                  float* __restrict__ loss) {
    __shared__ char lds[131616];
    char*  ldsE = lds;                       // fp8 swz [1024][128]
    int*   win  = (int*)  (lds + 131072);    // [128]
    float* rs   = (float*)(lds + 131584);    // [8]

    const int t = threadIdx.x, bm = blockIdx.x;     // 256 blocks
    const int lane = t & 63, w = t >> 6;            // 8 waves
    const int l15 = lane & 15, lg = lane >> 4;
    const int b = bm >> 3, hw0 = (bm & 7) << 7;     // 128 rows, line-aligned
    const int rot = bm & 15;                        // stagger phase

    // ---- stage full E image (128 KB), chunk order rotated per block ----
#pragma unroll
    for (int i = 0; i < 16; ++i) {
        int chunk = (i + rot) & 15;                 // 16 chunks of 8 KB
        int base = chunk * 8192 + (w << 10);        // wave-uniform byte base
        gload_lds16(Eb + base + lane * 16, ldsE + base);
    }

    // ---- A-frags direct from lat (regs), row-norm partial in same pass ----
    const float* lp = lat + ((size_t)b << 17) + hw0 + (w << 4) + l15;
    float xv[4][8];
#pragma unroll
    for (int ks = 0; ks < 4; ++ks)
#pragma unroll
        for (int j = 0; j < 8; ++j)
            xv[ks][j] = lp[(size_t)(ks * 32 + lg * 8 + j) << 10];

    float rn = 0.f;
    long av[4];
#pragma unroll
    for (int ks = 0; ks < 4; ++ks) {
#pragma unroll
        for (int j = 0; j < 8; ++j) rn = fmaf(xv[ks][j], xv[ks][j], rn);
        unsigned lo = cvt4_fp8(xv[ks][0], xv[ks][1], xv[ks][2], xv[ks][3]);
        unsigned hi = cvt4_fp8(xv[ks][4], xv[ks][5], xv[ks][6], xv[ks][7]);
        av[ks] = (long)(((unsigned long long)hi << 32) | lo);
    }
    __syncthreads();                 // E image resident (vmcnt drained)

    // ---- phase B: barrier-free sweep of all 1024 codes from LDS ----
    float run_s[4]; int run_i[4];
#pragma unroll
    for (int r = 0; r < 4; ++r) { run_s[r] = 3.0e38f; run_i[r] = 0; }

    for (int ct = 0; ct < 8; ++ct) {
        float cnv[8];
#pragma unroll
        for (int c = 0; c < 8; ++c) cnv[c] = cn[(ct << 7) + (c << 4) + l15];

        f32x4 acc[8];
#pragma unroll
        for (int c = 0; c < 8; ++c) acc[c] = (f32x4){0.f, 0.f, 0.f, 0.f};
#pragma unroll
        for (int ks = 0; ks < 4; ++ks) {
            long bv[8];
#pragma unroll
            for (int c = 0; c < 8; ++c) {
                int rr = (ct << 7) + (c << 4) + l15;
                bv[c] = *(const long*)(ldsE + rr * 128 +
                         ((ks * 32 + lg * 8) ^ ((rr & 7) << 4)));
            }
#pragma unroll
            for (int c = 0; c < 8; ++c)
                acc[c] = __builtin_amdgcn_mfma_f32_16x16x32_fp8_fp8(av[ks], bv[c], acc[c], 0, 0, 0);
        }
#pragma unroll
        for (int c = 0; c < 8; ++c) {
            int kg = (ct << 7) + (c << 4) + l15;
#pragma unroll
            for (int r = 0; r < 4; ++r) {
                float s = fmaf(NEG2_INV_LAMBDA, acc[c][r], cnv[c]);
                if (s < run_s[r]) { run_s[r] = s; run_i[r] = kg; }
            }
        }
    }

    // ---- in-wave merge: butterfly over 16 cols; win + loss partials ----
    float bs = 0.f;
#pragma unroll
    for (int r = 0; r < 4; ++r) {
        float s = run_s[r]; int bi = run_i[r];
#pragma unroll
        for (int mask = 1; mask < 16; mask <<= 1) {
            float os = __shfl_xor(s, mask);
            int   oi = __shfl_xor(bi, mask);
            if (os < s || (os == s && oi < bi)) { s = os; bi = oi; }
        }
        if (l15 == 0) {
            win[(w << 4) + (lg << 2) + r] = bi;    // C row = lg*4 + reg
            bs += s;
        }
    }
    {
        float v = ((l15 == 0) ? bs : 0.f) + rn;
#pragma unroll
        for (int m = 1; m < 64; m <<= 1) v += __shfl_xor(v, m);
        if (lane == 0) rs[w] = v;
    }
    __syncthreads();
    if (t == 0) {
        float v = rs[0] + rs[1] + rs[2] + rs[3] + rs[4] + rs[5] + rs[6] + rs[7];
        atomicAdd(loss, v * LOSS_SCALE);
    }

    // ---- gather q = emb[k*] fp32, store [B,D,H,W] coalesced ----
    {
        const int rowl = t & 127, dg = t >> 7;      // 4 dgrps x 32 d
        const int bi = win[rowl];
        const float4* eg = (const float4*)(emb + ((size_t)bi << 7) + (dg << 5));
        float* ob = outq + ((size_t)b << 17) + ((size_t)(dg << 5) << 10) + hw0 + rowl;
#pragma unroll
        for (int jj = 0; jj < 8; ++jj) {
            float4 v = eg[jj];
            ob[(size_t)(jj * 4 + 0) << 10] = v.x;
            ob[(size_t)(jj * 4 + 1) << 10] = v.y;
            ob[(size_t)(jj * 4 + 2) << 10] = v.z;
            ob[(size_t)(jj * 4 + 3) << 10] = v.w;
        }
    }
}

extern "C" void kernel_launch(void* const* d_in, const int* in_sizes, int n_in,
                              void* d_out, int out_size, void* d_ws, size_t ws_size,
                              hipStream_t stream) {
    const float* lat = (const float*)d_in[0];   // [32,128,32,32]
    const float* emb = (const float*)d_in[1];   // [1024,128]
    float* out = (float*)d_out;                 // q (4194304) + vq_loss (1)
    char* ws = (char*)d_ws;
    char*  E    = ws + WS_E;
    float* cn   = (float*)(ws + WS_C);
    float* loss = out + 4194304;

    k_prep <<<64,  256, 0, stream>>>(emb, E, cn, loss);
    k_fused<<<256, 512, 0, stream>>>(lat, emb, E, cn, out, loss);
}